// Round 8
// baseline (44.673 us; speedup 1.0000x reference)
//
#include <hip/hip_runtime.h>
#include <stdint.h>

#define IMG_H 512
#define IMG_W 512
#define NB 16
#define NC 8
#define HW (IMG_H * IMG_W)

#define TH 32                         // tile rows (vertical split x2 for occupancy)
#define TW 64                         // tile cols
#define HALO 15
#define CROWS (TH + 2 * HALO)         // 62 dilation rows (rel -15..46)
#define TROWS (TH + 32)               // 64 target rows  (rel -16..47)
#define TCOLS 96                      // target cols     (rel -16..79)
#define TSTRIDE 100                   // LDS row stride bytes (25 words, odd)
#define NTASK (CROWS * 3)             // 186 (row, word) tasks -> 1 per thread
#define NBLK (NB * 128)               // 2048 blocks = 8 per CU

typedef float f4 __attribute__((ext_vector_type(4)));

// ---------------------------------------------------------------------------
// FULLY FUSED kernel: boundary + distance transform + weighted CE per tile.
// One block per 32x64 tile (2048 blocks, 256 threads) -> 8 blocks/CU.
// STREAM-FIRST schedule: P0 target patch -> P1 boundary words -> CE stream
// (results held in registers; does NOT need dist) -> P2 dilations -> weight.
// The heavy memory stream starts right after the cheap P0/P1; the
// barrier-bound dilation runs after, overlapping other blocks' streams.
// ---------------------------------------------------------------------------
__global__ __launch_bounds__(256) void distce_kernel(const float* __restrict__ in,
                                                     const int* __restrict__ tgt,
                                                     float* __restrict__ partials) {
    __shared__ uint8_t  tg[TROWS][TSTRIDE];   // 6400 B
    __shared__ uint32_t cur[CROWS][5];        // 1240 B (stride 5: conflict-light)
    __shared__ uint8_t  dtile[TH][TW];        // 2048 B
    int b   = blockIdx.x >> 7;                // image
    int tid = blockIdx.x & 127;               // tile in image
    int ty = tid >> 3, tx = tid & 7;
    int ry = ty * TH, rx = tx * TW;
    int t = threadIdx.x;
    const int* tgtb = tgt + (size_t)b * HW;

    if (t < 128) ((uint4*)dtile)[t] = make_uint4(0u, 0u, 0u, 0u);

    // ---- P0: clamp-load 64x96 target patch (6144 = 24*256 elements) ----
    #pragma unroll
    for (int k = 0; k < 24; k++) {
        int tau = t + 256 * k;
        int r = tau / TCOLS, c = tau % TCOLS;
        int gy = min(max(ry - 16 + r, 0), IMG_H - 1);
        int gx = min(max(rx - 16 + c, 0), IMG_W - 1);
        tg[r][c] = (uint8_t)tgtb[gy * IMG_W + gx];
    }
    __syncthreads();

    // ---- P1: boundary bit words. word w bit i <-> rel col 32w+i-16 ----
    // (clamp-padding duplicates valid compares -> exact; bits at rel +-16
    //  edges are >=16 Chebyshev from the tile -> unreachable in 15 iters)
    if (t < NTASK) {
        int r = t / 3, w = t % 3;     // cur row r = rel row r-15
        int rr = r + 1;               // tg row of the center row
        int gy = ry - 15 + r;
        uint32_t word = 0u;
        if (gy >= 0 && gy < IMG_H) {
            uint32_t Wc[10], Wa[10], Wb[10];
            const uint32_t* pc = (const uint32_t*)&tg[rr][0];
            const uint32_t* pa = (const uint32_t*)&tg[rr - 1][0];
            const uint32_t* pb = (const uint32_t*)&tg[rr + 1][0];
            #pragma unroll
            for (int k = 0; k < 10; k++) {
                int idx = 8 * w - 1 + k;
                idx = min(max(idx, 0), 23);   // row = 24 words; edge bits dead
                Wc[k] = pc[idx]; Wa[k] = pa[idx]; Wb[k] = pb[idx];
            }
            #pragma unroll
            for (int i = 0; i < 8; i++) {
                uint32_t T = Wc[i + 1];
                uint32_t L = (Wc[i + 1] << 8) | (Wc[i] >> 24);
                uint32_t R = (Wc[i + 1] >> 8) | (Wc[i + 2] << 24);
                uint32_t a = (T ^ L) | (T ^ R);
                uint32_t C2 = Wa[i + 1];
                uint32_t L2 = (Wa[i + 1] << 8) | (Wa[i] >> 24);
                uint32_t R2 = (Wa[i + 1] >> 8) | (Wa[i + 2] << 24);
                a |= (T ^ C2) | (T ^ L2) | (T ^ R2);
                uint32_t C3 = Wb[i + 1];
                uint32_t L3 = (Wb[i + 1] << 8) | (Wb[i] >> 24);
                uint32_t R3 = (Wb[i + 1] >> 8) | (Wb[i + 2] << 24);
                a |= (T ^ C3) | (T ^ L3) | (T ^ R3);
                uint32_t t1  = (a & 0x7F7F7F7Fu) + 0x7F7F7F7Fu;
                uint32_t nzb = ((t1 | a) & 0x80808080u) >> 7;
                word |= (((nzb * 0x01020408u) >> 24) & 0xFu) << (4 * i);
            }
            if (tx == 0 && w == 0) word &= 0xFFFF0000u;   // gx<0 not in image
            if (tx == 7 && w == 2) word &= 0x0000FFFFu;   // gx>=512 not in image
        }
        cur[r][w] = word;
    }

    // ---- CE stream (needs tg, NOT dist): 8 px/thread, held in registers ----
    float cev[8];
    const float* inb = in + (size_t)b * NC * HW;
    #pragma unroll
    for (int g = 0; g < 2; g++) {
        int q = t + 256 * g;
        int row = q >> 4, quad = q & 15;
        const float* base = inb + (size_t)(ry + row) * IMG_W + rx + quad * 4;
        float v[NC][4];
        #pragma unroll
        for (int c = 0; c < NC; c++) {
            f4 f = *(const f4*)(base + (size_t)c * HW);
            v[c][0] = f.x; v[c][1] = f.y; v[c][2] = f.z; v[c][3] = f.w;
        }
        uint32_t tw = ((const uint32_t*)&tg[16 + row][0])[4 + quad];
        #pragma unroll
        for (int j = 0; j < 4; j++) {
            float mx = v[0][j];
            #pragma unroll
            for (int c = 1; c < NC; c++) mx = fmaxf(mx, v[c][j]);
            float s = 0.0f;
            #pragma unroll
            for (int c = 0; c < NC; c++) s += __expf(v[c][j] - mx);
            float lse = mx + __logf(s);
            int tc = (int)((tw >> (8 * j)) & 0xFFu);
            float lt = v[0][j];
            #pragma unroll
            for (int c = 1; c < NC; c++) lt = (tc == c) ? v[c][j] : lt;
            cev[g * 4 + j] = lse - lt;
        }
    }
    __syncthreads();   // cur[] fully written; CE regs independent

    // ---- P2: 15 bit-parallel dilations; new bits -> dtile ----
    int r0 = t / 3, w0 = t % 3;
    bool has0 = t < NTASK;
    const uint32_t livemask[3] = {0xFFFF0000u, 0xFFFFFFFFu, 0x0000FFFFu};
    for (int it = 1; it <= 15; it++) {
        uint32_t n0 = 0u, o0 = 0u;
        if (has0) {
            o0 = cur[r0][w0];
            #pragma unroll
            for (int dr = -1; dr <= 1; dr++) {
                int rr2 = r0 + dr;
                if ((unsigned)rr2 >= (unsigned)CROWS) continue;
                uint32_t v  = cur[rr2][w0];
                uint32_t lf = (w0 > 0) ? cur[rr2][w0 - 1] : 0u;
                uint32_t rg = (w0 < 2) ? cur[rr2][w0 + 1] : 0u;
                n0 |= v | (v << 1) | (v >> 1) | (lf >> 31) | (rg << 31);
            }
        }
        __syncthreads();
        if (has0) {
            cur[r0][w0] = n0;
            if (r0 >= HALO && r0 < HALO + TH) {
                uint32_t nb = (n0 & ~o0) & livemask[w0];
                while (nb) { int bit = __ffs(nb) - 1; nb &= nb - 1;
                             dtile[r0 - HALO][w0 * 32 + bit - 16] = (uint8_t)it; }
            }
        }
        __syncthreads();
    }

    // ---- weight by exp(-dist/5) and reduce ----
    float partial = 0.0f;
    #pragma unroll
    for (int g = 0; g < 2; g++) {
        int q = t + 256 * g;
        int row = q >> 4, quad = q & 15;
        uint32_t d4 = *(const uint32_t*)&dtile[row][quad * 4];
        #pragma unroll
        for (int j = 0; j < 4; j++) {
            float d = (float)((d4 >> (8 * j)) & 0xFFu);
            partial += __expf(d * -0.2f) * cev[g * 4 + j];
        }
    }
    #pragma unroll
    for (int off = 32; off > 0; off >>= 1) partial += __shfl_down(partial, off);
    __shared__ float wsums[4];
    int lane = t & 63;
    int wid = t >> 6;
    if (lane == 0) wsums[wid] = partial;
    __syncthreads();
    if (t == 0)
        partials[blockIdx.x] = wsums[0] + wsums[1] + wsums[2] + wsums[3];
}

// ---------------------------------------------------------------------------
// Deterministic tree-reduce of 2048 partials -> mean. One block.
// ---------------------------------------------------------------------------
__global__ __launch_bounds__(256) void reduce_kernel(const float* __restrict__ partials,
                                                     float* __restrict__ out) {
    double s = 0.0;
    #pragma unroll
    for (int i = 0; i < NBLK / 256; i++)
        s += (double)partials[threadIdx.x + 256 * i];
    #pragma unroll
    for (int off = 32; off > 0; off >>= 1) s += __shfl_down(s, off);
    __shared__ double wsums[4];
    int lane = threadIdx.x & 63;
    int wid = threadIdx.x >> 6;
    if (lane == 0) wsums[wid] = s;
    __syncthreads();
    if (threadIdx.x == 0) {
        double tot = wsums[0] + wsums[1] + wsums[2] + wsums[3];
        out[0] = (float)(tot * (1.0 / (double)((size_t)NB * HW)));
    }
}

extern "C" void kernel_launch(void* const* d_in, const int* in_sizes, int n_in,
                              void* d_out, int out_size, void* d_ws, size_t ws_size,
                              hipStream_t stream) {
    const float* in  = (const float*)d_in[0];
    const int*   tgt = (const int*)d_in[1];
    float* out = (float*)d_out;

    float* partials = (float*)((char*)d_ws + 256);   // 8 KB

    distce_kernel<<<NBLK, 256, 0, stream>>>(in, tgt, partials);
    reduce_kernel<<<1, 256, 0, stream>>>(partials, out);
}